// Round 1
// baseline (1067.646 us; speedup 1.0000x reference)
//
#include <hip/hip_runtime.h>

#define TWO_PI 6.28318530717958647692f

// Problem: B=32, M=N=128, I=O=64, NM=16.
// Spectral path keeps only km in {0..15, 112..127} (p=0..31) and kn=0..15 (q).
//
// ws layout (floats):
//   w0t  @ 0        : 262144  (32 p x 64 i x 64 j complex, first-factor weights)
//   w1t  @ 262144   : 262144  (2 h x 16 kv x 64 j x 64 o complex, second factor)
//   T    @ 524288   : 8388608 ([b][u][q][o] complex)
//   A    @ 8912896  : 8388608 ([b][m][kv][i] complex)        (dead after k2)
//   xft  @ 17301504 : 2097152 ([b][p][kv][i] complex)        (dead after k3a)
//   c1   @ 19398656 : 2097152                                 (dead after k3b)
//   oft  @ 21495808 : 2097152                                 (dead after k4)
//   y    @ 8912896  : 33554432 (overlays A..oft, all dead by k5)
// total needed: 42467328 floats = 162 MiB

__global__ __launch_bounds__(256) void k0_prep(const float* __restrict__ ws0,
                                               const float* __restrict__ ws1,
                                               float2* __restrict__ w0t,
                                               float2* __restrict__ w1t)
{
    int tgt = blockIdx.x * 256 + threadIdx.x;   // 0..262143
    if (tgt < 131072) {
        int p = tgt >> 12;
        int rem = tgt & 4095;
        int i = rem >> 6, j = rem & 63;
        const float* s = (p < 16) ? ws0 : ws1;   // f=0 plane
        int px = p & 15;
        int base = ((i * 64 + j) * 16 + px) * 2;
        w0t[tgt] = make_float2(s[base], s[base + 1]);
    } else {
        int u = tgt - 131072;
        int h = u >> 16;
        int kv = (u >> 12) & 15;
        int j = (u >> 6) & 63;
        int o = u & 63;
        const float* s = (h ? ws1 : ws0) + 131072;  // f=1 plane
        int base = ((j * 64 + o) * 16 + kv) * 2;
        w1t[u] = make_float2(s[base], s[base + 1]);
    }
}

// k1: A[b,m,kv,i] = sum_n x[b,m,n,i] * exp(-2pi i kv n/128), kv=0..15
__global__ __launch_bounds__(256) void k1_dft_n(const float* __restrict__ x,
                                                float2* __restrict__ A)
{
    __shared__ float Xs[128][64];
    __shared__ float tc[128], tsn[128];
    const int t = threadIdx.x;
    const int bm = blockIdx.x;
    if (t < 128) { float a = t * (TWO_PI / 128.0f); tc[t] = cosf(a); tsn[t] = sinf(a); }
    const float4* xg4 = (const float4*)(x + (size_t)bm * 8192);
    float4* Xs4 = (float4*)&Xs[0][0];
    for (int k = t; k < 2048; k += 256) Xs4[k] = xg4[k];
    __syncthreads();
    const int i = t & 63;
    const int kv0 = (t >> 6) << 2;
    float re[4] = {0.f, 0.f, 0.f, 0.f}, im[4] = {0.f, 0.f, 0.f, 0.f};
    for (int n = 0; n < 128; ++n) {
        float v = Xs[n][i];
        #pragma unroll
        for (int j = 0; j < 4; ++j) {
            int idx = ((kv0 + j) * n) & 127;
            re[j] += v * tc[idx];
            im[j] -= v * tsn[idx];
        }
    }
    float2* Ap = A + (size_t)bm * 1024;
    #pragma unroll
    for (int j = 0; j < 4; ++j) Ap[(kv0 + j) * 64 + i] = make_float2(re[j], im[j]);
}

// k2: xft[b,p,kv,i] = (1/128) sum_m A[b,m,kv,i] * exp(-2pi i km(p) m/128)
__global__ __launch_bounds__(256) void k2_dft_m(const float2* __restrict__ A,
                                                float2* __restrict__ xft)
{
    __shared__ float2 As[128][64];
    __shared__ float tc[128], tsn[128];
    const int t = threadIdx.x;
    const int b = blockIdx.x >> 4, kv = blockIdx.x & 15;
    if (t < 128) { float a = t * (TWO_PI / 128.0f); tc[t] = cosf(a); tsn[t] = sinf(a); }
    for (int k = t; k < 8192; k += 256) {
        int m = k >> 6, i = k & 63;
        As[m][i] = A[((size_t)(b * 128 + m) * 16 + kv) * 64 + i];
    }
    __syncthreads();
    const int i = t & 63;
    const int p0 = (t >> 6) << 3;
    float2 acc[8];
    #pragma unroll
    for (int j = 0; j < 8; ++j) acc[j] = make_float2(0.f, 0.f);
    for (int m = 0; m < 128; ++m) {
        float2 a = As[m][i];
        #pragma unroll
        for (int j = 0; j < 8; ++j) {
            int p = p0 + j;
            int km = (p < 16) ? p : (96 + p);     // p>=16 -> km = 112 + (p-16)
            int idx = (km * m) & 127;
            float c = tc[idx], s = tsn[idx];
            acc[j].x += a.x * c + a.y * s;        // a * e^{-i th}
            acc[j].y += a.y * c - a.x * s;
        }
    }
    const float sc = 1.0f / 128.0f;
    #pragma unroll
    for (int j = 0; j < 8; ++j)
        xft[((size_t)(b * 32 + p0 + j) * 16 + kv) * 64 + i] =
            make_float2(acc[j].x * sc, acc[j].y * sc);
}

// k3a: c1[b,p,kv,j] = sum_i xft[b,p,kv,i] * w0c[i,j,p]
__global__ __launch_bounds__(256) void k3a_spec1(const float2* __restrict__ xft,
                                                 const float2* __restrict__ w0t,
                                                 float2* __restrict__ c1)
{
    __shared__ __align__(16) float2 xs[16][64];
    __shared__ __align__(16) float2 w0s[64][64];
    const int t = threadIdx.x;
    const int b = blockIdx.x >> 5, p = blockIdx.x & 31;
    const float2* xg = xft + (size_t)(b * 32 + p) * 1024;
    for (int k = t; k < 1024; k += 256) ((float2*)xs)[k] = xg[k];
    const float4* wg = (const float4*)(w0t + (size_t)p * 4096);
    for (int k = t; k < 2048; k += 256) ((float4*)w0s)[k] = wg[k];
    __syncthreads();
    const int j = t & 63;
    const int kv0 = (t >> 6) << 2;
    float2 acc[4];
    #pragma unroll
    for (int q = 0; q < 4; ++q) acc[q] = make_float2(0.f, 0.f);
    for (int i = 0; i < 64; ++i) {
        float2 w = w0s[i][j];
        #pragma unroll
        for (int q = 0; q < 4; ++q) {
            float2 a = xs[kv0 + q][i];
            acc[q].x += a.x * w.x - a.y * w.y;
            acc[q].y += a.x * w.y + a.y * w.x;
        }
    }
    #pragma unroll
    for (int q = 0; q < 4; ++q)
        c1[((size_t)(b * 32 + p) * 16 + kv0 + q) * 64 + j] = acc[q];
}

// k3b: oft[b,p,kv,o] = sum_j c1[b,p,kv,j] * w1c[j,o,kv]  (weights per half h=p/16)
__global__ __launch_bounds__(256) void k3b_spec2(const float2* __restrict__ c1,
                                                 const float2* __restrict__ w1t,
                                                 float2* __restrict__ oft)
{
    __shared__ __align__(16) float2 cs[16][64];
    __shared__ __align__(16) float2 w1s[64][64];
    const int t = threadIdx.x;
    int id = blockIdx.x;
    const int h = id & 1; id >>= 1;
    const int kv = id & 15; const int b = id >> 4;
    for (int k = t; k < 1024; k += 256) {
        int pp = k >> 6, j = k & 63;
        cs[pp][j] = c1[((size_t)(b * 32 + h * 16 + pp) * 16 + kv) * 64 + j];
    }
    const float4* wg = (const float4*)(w1t + (size_t)(h * 16 + kv) * 4096);
    for (int k = t; k < 2048; k += 256) ((float4*)w1s)[k] = wg[k];
    __syncthreads();
    const int o = t & 63;
    const int pp0 = (t >> 6) << 2;
    float2 acc[4];
    #pragma unroll
    for (int q = 0; q < 4; ++q) acc[q] = make_float2(0.f, 0.f);
    for (int j = 0; j < 64; ++j) {
        float2 w = w1s[j][o];
        #pragma unroll
        for (int q = 0; q < 4; ++q) {
            float2 a = cs[pp0 + q][j];
            acc[q].x += a.x * w.x - a.y * w.y;
            acc[q].y += a.x * w.y + a.y * w.x;
        }
    }
    #pragma unroll
    for (int q = 0; q < 4; ++q)
        oft[((size_t)(b * 32 + h * 16 + pp0 + q) * 16 + kv) * 64 + o] = acc[q];
}

// k4: T[b,u,q,o] = sum_p oft[b,p,q,o] * exp(+2pi i km(p) u/128)
__global__ __launch_bounds__(256) void k4_idft_m(const float2* __restrict__ oft,
                                                 float2* __restrict__ T)
{
    __shared__ float2 Os[32][64];
    __shared__ float tc[128], tsn[128];
    const int t = threadIdx.x;
    const int b = blockIdx.x >> 4, q = blockIdx.x & 15;
    if (t < 128) { float a = t * (TWO_PI / 128.0f); tc[t] = cosf(a); tsn[t] = sinf(a); }
    for (int k = t; k < 2048; k += 256) {
        int p = k >> 6, o = k & 63;
        Os[p][o] = oft[((size_t)(b * 32 + p) * 16 + q) * 64 + o];
    }
    __syncthreads();
    const int o = t & 63;
    const int u0 = (t >> 6) << 5;
    float2 op[32];
    #pragma unroll
    for (int p = 0; p < 32; ++p) op[p] = Os[p][o];
    for (int du = 0; du < 32; ++du) {
        int u = u0 + du;
        float ax = 0.f, ay = 0.f;
        #pragma unroll
        for (int p = 0; p < 32; ++p) {
            int km = (p < 16) ? p : (96 + p);
            int idx = (km * u) & 127;
            float c = tc[idx], s = tsn[idx];
            ax += op[p].x * c - op[p].y * s;      // a * e^{+i th}
            ay += op[p].x * s + op[p].y * c;
        }
        T[((size_t)(b * 128 + u) * 16 + q) * 64 + o] = make_float2(ax, ay);
    }
}

// k5: y[b,u,v,o] = relu( (1/128)*(Re T[u,0,o] + 2*sum_{q=1..15} Re(T[u,q,o] e^{2pi i q v/128}))
//                        + sum_i x[b,u,v,i]*w_lin[i,o] + b_lin[o] )
__global__ __launch_bounds__(256) void k5_assemble(const float* __restrict__ x,
                                                   const float2* __restrict__ T,
                                                   const float* __restrict__ wl,
                                                   const float* __restrict__ bl,
                                                   float* __restrict__ y)
{
    __shared__ float xs[128][65];
    __shared__ __align__(16) float2 Ts[16][64];
    __shared__ __align__(16) float wls[64 * 64];
    __shared__ float bls[64];
    __shared__ float tc[128], tsn[128];
    const int t = threadIdx.x;
    const int bm = blockIdx.x;   // b*128 + u
    if (t < 128) { float a = t * (TWO_PI / 128.0f); tc[t] = cosf(a); tsn[t] = sinf(a); }
    const float4* xg4 = (const float4*)(x + (size_t)bm * 8192);
    for (int k = t; k < 2048; k += 256) {
        float4 v = xg4[k]; int r = k >> 4, c = (k & 15) << 2;
        xs[r][c] = v.x; xs[r][c + 1] = v.y; xs[r][c + 2] = v.z; xs[r][c + 3] = v.w;
    }
    const float2* Tg = T + (size_t)bm * 1024;
    for (int k = t; k < 1024; k += 256) ((float2*)Ts)[k] = Tg[k];
    for (int k = t; k < 1024; k += 256) ((float4*)wls)[k] = ((const float4*)wl)[k];
    if (t < 64) bls[t] = bl[t];
    __syncthreads();
    const int o0 = (t & 15) << 2;
    const int vb = t >> 4;               // v = vb + 16*vv
    float acc[8][4];
    #pragma unroll
    for (int vv = 0; vv < 8; ++vv)
        #pragma unroll
        for (int oo = 0; oo < 4; ++oo) acc[vv][oo] = bls[o0 + oo];
    for (int i = 0; i < 64; ++i) {
        float w[4];
        *(float4*)w = *(const float4*)&wls[i * 64 + o0];
        #pragma unroll
        for (int vv = 0; vv < 8; ++vv) {
            float xv = xs[vb + 16 * vv][i];
            #pragma unroll
            for (int oo = 0; oo < 4; ++oo) acc[vv][oo] += xv * w[oo];
        }
    }
    {   // q = 0 term (irfft keeps only the real part of the DC bin)
        float t0[4];
        #pragma unroll
        for (int oo = 0; oo < 4; ++oo) t0[oo] = Ts[0][o0 + oo].x * (1.0f / 128.0f);
        #pragma unroll
        for (int vv = 0; vv < 8; ++vv)
            #pragma unroll
            for (int oo = 0; oo < 4; ++oo) acc[vv][oo] += t0[oo];
    }
    for (int q = 1; q < 16; ++q) {
        float2 tq[4];
        #pragma unroll
        for (int oo = 0; oo < 4; ++oo) tq[oo] = Ts[q][o0 + oo];
        #pragma unroll
        for (int vv = 0; vv < 8; ++vv) {
            int idx = (q * (vb + 16 * vv)) & 127;
            float c = tc[idx] * (1.0f / 64.0f);   // 2/128
            float s = tsn[idx] * (1.0f / 64.0f);
            #pragma unroll
            for (int oo = 0; oo < 4; ++oo)
                acc[vv][oo] += tq[oo].x * c - tq[oo].y * s;
        }
    }
    float* yg = y + (size_t)bm * 8192;
    #pragma unroll
    for (int vv = 0; vv < 8; ++vv) {
        int v = vb + 16 * vv;
        float4 r;
        r.x = fmaxf(acc[vv][0], 0.f); r.y = fmaxf(acc[vv][1], 0.f);
        r.z = fmaxf(acc[vv][2], 0.f); r.w = fmaxf(acc[vv][3], 0.f);
        *(float4*)&yg[v * 64 + o0] = r;
    }
}

// k6: both heads fused: out_h = relu(y@W1+b1)@W2+b2, 64 rows per block
__global__ __launch_bounds__(256) void k6_heads(const float* __restrict__ y,
    const float* __restrict__ wb1, const float* __restrict__ bb1,
    const float* __restrict__ wb2, const float* __restrict__ bb2,
    const float* __restrict__ wf1, const float* __restrict__ bf1,
    const float* __restrict__ wf2, const float* __restrict__ bf2,
    float* __restrict__ out)
{
    __shared__ float ys[64][65];
    __shared__ float hs[64][129];
    __shared__ __align__(16) float w1s[64 * 128];
    __shared__ __align__(16) float w2s[128 * 64];
    __shared__ float b1s[128];
    __shared__ float b2s[64];
    const int t = threadIdx.x;
    const size_t rbase = (size_t)blockIdx.x * 64;
    const float4* yg4 = (const float4*)(y + rbase * 64);
    for (int k = t; k < 1024; k += 256) {
        float4 v = yg4[k]; int r = k >> 4, c = (k & 15) << 2;
        ys[r][c] = v.x; ys[r][c + 1] = v.y; ys[r][c + 2] = v.z; ys[r][c + 3] = v.w;
    }
    const int r0 = (t >> 4) << 2;   // 0..60
    const int c0 = (t & 15) << 3;   // 0..120
    const int o0 = (t & 15) << 2;   // 0..60
    for (int head = 0; head < 2; ++head) {
        const float* W1 = head ? wf1 : wb1;
        const float* B1 = head ? bf1 : bb1;
        const float* W2 = head ? wf2 : wb2;
        const float* B2 = head ? bf2 : bb2;
        __syncthreads();   // ys loaded; prev head's phase2 done before W overwrite
        for (int k = t; k < 2048; k += 256) ((float4*)w1s)[k] = ((const float4*)W1)[k];
        for (int k = t; k < 2048; k += 256) ((float4*)w2s)[k] = ((const float4*)W2)[k];
        if (t < 128) b1s[t] = B1[t];
        if (t < 64) b2s[t] = B2[t];
        __syncthreads();
        // phase 1: h = relu(ys @ W1 + b1)  (64x128)
        float acc[4][8];
        #pragma unroll
        for (int rr = 0; rr < 4; ++rr)
            #pragma unroll
            for (int cc = 0; cc < 8; ++cc) acc[rr][cc] = b1s[c0 + cc];
        for (int i = 0; i < 64; ++i) {
            float w[8];
            *(float4*)&w[0] = *(const float4*)&w1s[i * 128 + c0];
            *(float4*)&w[4] = *(const float4*)&w1s[i * 128 + c0 + 4];
            float yv[4];
            #pragma unroll
            for (int rr = 0; rr < 4; ++rr) yv[rr] = ys[r0 + rr][i];
            #pragma unroll
            for (int rr = 0; rr < 4; ++rr)
                #pragma unroll
                for (int cc = 0; cc < 8; ++cc) acc[rr][cc] += yv[rr] * w[cc];
        }
        #pragma unroll
        for (int rr = 0; rr < 4; ++rr)
            #pragma unroll
            for (int cc = 0; cc < 8; ++cc)
                hs[r0 + rr][c0 + cc] = fmaxf(acc[rr][cc], 0.f);
        __syncthreads();
        // phase 2: out = h @ W2 + b2  (64x64)
        float acc2[4][4];
        #pragma unroll
        for (int rr = 0; rr < 4; ++rr)
            #pragma unroll
            for (int oo = 0; oo < 4; ++oo) acc2[rr][oo] = b2s[o0 + oo];
        for (int c = 0; c < 128; ++c) {
            float w[4];
            *(float4*)w = *(const float4*)&w2s[c * 64 + o0];
            float hv[4];
            #pragma unroll
            for (int rr = 0; rr < 4; ++rr) hv[rr] = hs[r0 + rr][c];
            #pragma unroll
            for (int rr = 0; rr < 4; ++rr)
                #pragma unroll
                for (int oo = 0; oo < 4; ++oo) acc2[rr][oo] += hv[rr] * w[oo];
        }
        float* og = out + (size_t)head * 33554432u + rbase * 64;
        #pragma unroll
        for (int rr = 0; rr < 4; ++rr)
            *(float4*)&og[(r0 + rr) * 64 + o0] =
                make_float4(acc2[rr][0], acc2[rr][1], acc2[rr][2], acc2[rr][3]);
    }
}

extern "C" void kernel_launch(void* const* d_in, const int* in_sizes, int n_in,
                              void* d_out, int out_size, void* d_ws, size_t ws_size,
                              hipStream_t stream)
{
    (void)in_sizes; (void)n_in; (void)out_size; (void)ws_size;
    const float* x   = (const float*)d_in[0];
    const float* ws0 = (const float*)d_in[1];
    const float* ws1 = (const float*)d_in[2];
    const float* wl  = (const float*)d_in[3];
    const float* bl  = (const float*)d_in[4];
    const float* wb1 = (const float*)d_in[5];
    const float* bb1 = (const float*)d_in[6];
    const float* wb2 = (const float*)d_in[7];
    const float* bb2 = (const float*)d_in[8];
    const float* wf1 = (const float*)d_in[9];
    const float* bf1 = (const float*)d_in[10];
    const float* wf2 = (const float*)d_in[11];
    const float* bf2 = (const float*)d_in[12];
    float* out = (float*)d_out;

    float* ws = (float*)d_ws;
    float2* w0t = (float2*)ws;                    // 131072 float2
    float2* w1t = (float2*)(ws + 262144);         // 131072 float2
    float2* Tb  = (float2*)(ws + 524288);         // 4194304 float2
    float2* Ab  = (float2*)(ws + 8912896);        // 4194304 float2
    float2* xft = (float2*)(ws + 17301504);       // 1048576 float2
    float2* c1b = (float2*)(ws + 19398656);       // 1048576 float2
    float2* oft = (float2*)(ws + 21495808);       // 1048576 float2
    float*  yb  = ws + 8912896;                   // 33554432 floats, overlays A..oft

    k0_prep   <<<1024, 256, 0, stream>>>(ws0, ws1, w0t, w1t);
    k1_dft_n  <<<4096, 256, 0, stream>>>(x, Ab);
    k2_dft_m  <<<512,  256, 0, stream>>>(Ab, xft);
    k3a_spec1 <<<1024, 256, 0, stream>>>(xft, w0t, c1b);
    k3b_spec2 <<<1024, 256, 0, stream>>>(c1b, w1t, oft);
    k4_idft_m <<<512,  256, 0, stream>>>(oft, Tb);
    k5_assemble<<<4096, 256, 0, stream>>>(x, Tb, wl, bl, yb);
    k6_heads  <<<8192, 256, 0, stream>>>(yb, wb1, bb1, wb2, bb2, wf1, bf1, wf2, bf2, out);
}

// Round 3
// 464.927 us; speedup vs baseline: 2.2964x; 2.2964x over previous
//
#include <hip/hip_runtime.h>
#include <hip/hip_bf16.h>

#define TWO_PI 6.28318530717958647692f

typedef __attribute__((ext_vector_type(8))) short bf16x8;
typedef __attribute__((ext_vector_type(4))) float f32x4;

__device__ __forceinline__ unsigned short f2bf(float v) {
    __hip_bfloat16 h = __float2bfloat16(v);
    return *(unsigned short*)&h;
}

// Problem: B=32, M=N=128, I=O=64, NM=16.
// Spectral path keeps only km in {0..15, 112..127} (p=0..31) and kn=0..15 (q).
//
// ws layout (float offsets):
//   w0t  @ 0        : 262144   (32 p x 64 i x 64 j complex)
//   w1t  @ 262144   : 262144   (2 h x 16 kv x 64 j x 64 o complex)
//   T    @ 524288   : 8388608  ([b][u][q][o] complex)
//   A    @ 8912896  : 8388608  ([b][m][kv][i] complex)   (dead after k2)
//   y    @ 8912896  : 33554432 bf16 = 16777216 float-equiv, spans [8912896,25690112)
//        overlays A, xft, c1, oft — ALL dead by k5. (Round-2 bug: wbt was at
//        23592960, inside y's span, so k5 clobbered the head weights.)
//   xft  @ 17301504 : 2097152  (dead after k3a)
//   c1   @ 19398656 : 2097152  (dead after k3b)
//   oft  @ 21495808 : 2097152  (dead after k4)
//   wbt  @ 25690112 : 32768 bf16 W1t + 32768 bf16 W2t  (PAST y's end)
// total: 25706496 floats = 98 MiB (round 1 proved ws_size >= 162 MiB)

__global__ __launch_bounds__(256) void k0_prep(const float* __restrict__ ws0,
                                               const float* __restrict__ ws1,
                                               float2* __restrict__ w0t,
                                               float2* __restrict__ w1t)
{
    int tgt = blockIdx.x * 256 + threadIdx.x;   // 0..262143
    if (tgt < 131072) {
        int p = tgt >> 12;
        int rem = tgt & 4095;
        int i = rem >> 6, j = rem & 63;
        const float* s = (p < 16) ? ws0 : ws1;   // f=0 plane
        int px = p & 15;
        int base = ((i * 64 + j) * 16 + px) * 2;
        w0t[tgt] = make_float2(s[base], s[base + 1]);
    } else {
        int u = tgt - 131072;
        int h = u >> 16;
        int kv = (u >> 12) & 15;
        int j = (u >> 6) & 63;
        int o = u & 63;
        const float* s = (h ? ws1 : ws0) + 131072;  // f=1 plane
        int base = ((j * 64 + o) * 16 + kv) * 2;
        w1t[u] = make_float2(s[base], s[base + 1]);
    }
}

// bf16 transposed head weights: W1t[head][o:128][k:64], W2t[head][o:64][k:128]
__global__ __launch_bounds__(256) void k0b_prep(const float* __restrict__ wb1,
                                                const float* __restrict__ wf1,
                                                const float* __restrict__ wb2,
                                                const float* __restrict__ wf2,
                                                unsigned short* __restrict__ w1bt,
                                                unsigned short* __restrict__ w2bt)
{
    int tgt = blockIdx.x * 256 + threadIdx.x;   // 0..32767
    if (tgt < 16384) {
        int head = tgt >> 13;
        int o = (tgt >> 6) & 127;
        int i = tgt & 63;
        const float* src = head ? wf1 : wb1;    // [64][128]
        w1bt[tgt] = f2bf(src[i * 128 + o]);
    } else {
        int u = tgt - 16384;
        int head = u >> 13;
        int o = (u >> 7) & 63;
        int c = u & 127;
        const float* src = head ? wf2 : wb2;    // [128][64]
        w2bt[u] = f2bf(src[c * 64 + o]);
    }
}

// k1: A[b,m,kv,i] = sum_n x[b,m,n,i] * exp(-2pi i kv n/128), kv=0..15
__global__ __launch_bounds__(256) void k1_dft_n(const float* __restrict__ x,
                                                float2* __restrict__ A)
{
    __shared__ float Xs[128][64];
    __shared__ float tc[128], tsn[128];
    const int t = threadIdx.x;
    const int bm = blockIdx.x;
    if (t < 128) { float a = t * (TWO_PI / 128.0f); tc[t] = cosf(a); tsn[t] = sinf(a); }
    const float4* xg4 = (const float4*)(x + (size_t)bm * 8192);
    float4* Xs4 = (float4*)&Xs[0][0];
    for (int k = t; k < 2048; k += 256) Xs4[k] = xg4[k];
    __syncthreads();
    const int i = t & 63;
    const int kv0 = (t >> 6) << 2;
    float re[4] = {0.f, 0.f, 0.f, 0.f}, im[4] = {0.f, 0.f, 0.f, 0.f};
    for (int n = 0; n < 128; ++n) {
        float v = Xs[n][i];
        #pragma unroll
        for (int j = 0; j < 4; ++j) {
            int idx = ((kv0 + j) * n) & 127;
            re[j] += v * tc[idx];
            im[j] -= v * tsn[idx];
        }
    }
    float2* Ap = A + (size_t)bm * 1024;
    #pragma unroll
    for (int j = 0; j < 4; ++j) Ap[(kv0 + j) * 64 + i] = make_float2(re[j], im[j]);
}

// k2: xft[b,p,kv,i] = (1/128) sum_m A[b,m,kv,i] * exp(-2pi i km(p) m/128)
__global__ __launch_bounds__(256) void k2_dft_m(const float2* __restrict__ A,
                                                float2* __restrict__ xft)
{
    __shared__ float2 As[128][64];
    __shared__ float tc[128], tsn[128];
    const int t = threadIdx.x;
    const int b = blockIdx.x >> 4, kv = blockIdx.x & 15;
    if (t < 128) { float a = t * (TWO_PI / 128.0f); tc[t] = cosf(a); tsn[t] = sinf(a); }
    for (int k = t; k < 8192; k += 256) {
        int m = k >> 6, i = k & 63;
        As[m][i] = A[((size_t)(b * 128 + m) * 16 + kv) * 64 + i];
    }
    __syncthreads();
    const int i = t & 63;
    const int p0 = (t >> 6) << 3;
    float2 acc[8];
    #pragma unroll
    for (int j = 0; j < 8; ++j) acc[j] = make_float2(0.f, 0.f);
    for (int m = 0; m < 128; ++m) {
        float2 a = As[m][i];
        #pragma unroll
        for (int j = 0; j < 8; ++j) {
            int p = p0 + j;
            int km = (p < 16) ? p : (96 + p);     // p>=16 -> km = 112 + (p-16)
            int idx = (km * m) & 127;
            float c = tc[idx], s = tsn[idx];
            acc[j].x += a.x * c + a.y * s;        // a * e^{-i th}
            acc[j].y += a.y * c - a.x * s;
        }
    }
    const float sc = 1.0f / 128.0f;
    #pragma unroll
    for (int j = 0; j < 8; ++j)
        xft[((size_t)(b * 32 + p0 + j) * 16 + kv) * 64 + i] =
            make_float2(acc[j].x * sc, acc[j].y * sc);
}

// k3a: c1[b,p,kv,j] = sum_i xft[b,p,kv,i] * w0c[i,j,p]
__global__ __launch_bounds__(256) void k3a_spec1(const float2* __restrict__ xft,
                                                 const float2* __restrict__ w0t,
                                                 float2* __restrict__ c1)
{
    __shared__ __align__(16) float2 xs[16][64];
    __shared__ __align__(16) float2 w0s[64][64];
    const int t = threadIdx.x;
    const int b = blockIdx.x >> 5, p = blockIdx.x & 31;
    const float2* xg = xft + (size_t)(b * 32 + p) * 1024;
    for (int k = t; k < 1024; k += 256) ((float2*)xs)[k] = xg[k];
    const float4* wg = (const float4*)(w0t + (size_t)p * 4096);
    for (int k = t; k < 2048; k += 256) ((float4*)w0s)[k] = wg[k];
    __syncthreads();
    const int j = t & 63;
    const int kv0 = (t >> 6) << 2;
    float2 acc[4];
    #pragma unroll
    for (int q = 0; q < 4; ++q) acc[q] = make_float2(0.f, 0.f);
    for (int i = 0; i < 64; ++i) {
        float2 w = w0s[i][j];
        #pragma unroll
        for (int q = 0; q < 4; ++q) {
            float2 a = xs[kv0 + q][i];
            acc[q].x += a.x * w.x - a.y * w.y;
            acc[q].y += a.x * w.y + a.y * w.x;
        }
    }
    #pragma unroll
    for (int q = 0; q < 4; ++q)
        c1[((size_t)(b * 32 + p) * 16 + kv0 + q) * 64 + j] = acc[q];
}

// k3b: oft[b,p,kv,o] = sum_j c1[b,p,kv,j] * w1c[j,o,kv]  (weights per half h=p/16)
__global__ __launch_bounds__(256) void k3b_spec2(const float2* __restrict__ c1,
                                                 const float2* __restrict__ w1t,
                                                 float2* __restrict__ oft)
{
    __shared__ __align__(16) float2 cs[16][64];
    __shared__ __align__(16) float2 w1s[64][64];
    const int t = threadIdx.x;
    int id = blockIdx.x;
    const int h = id & 1; id >>= 1;
    const int kv = id & 15; const int b = id >> 4;
    for (int k = t; k < 1024; k += 256) {
        int pp = k >> 6, j = k & 63;
        cs[pp][j] = c1[((size_t)(b * 32 + h * 16 + pp) * 16 + kv) * 64 + j];
    }
    const float4* wg = (const float4*)(w1t + (size_t)(h * 16 + kv) * 4096);
    for (int k = t; k < 2048; k += 256) ((float4*)w1s)[k] = wg[k];
    __syncthreads();
    const int o = t & 63;
    const int pp0 = (t >> 6) << 2;
    float2 acc[4];
    #pragma unroll
    for (int q = 0; q < 4; ++q) acc[q] = make_float2(0.f, 0.f);
    for (int j = 0; j < 64; ++j) {
        float2 w = w1s[j][o];
        #pragma unroll
        for (int q = 0; q < 4; ++q) {
            float2 a = cs[pp0 + q][j];
            acc[q].x += a.x * w.x - a.y * w.y;
            acc[q].y += a.x * w.y + a.y * w.x;
        }
    }
    #pragma unroll
    for (int q = 0; q < 4; ++q)
        oft[((size_t)(b * 32 + h * 16 + pp0 + q) * 16 + kv) * 64 + o] = acc[q];
}

// k4: T[b,u,q,o] = sum_p oft[b,p,q,o] * exp(+2pi i km(p) u/128)
__global__ __launch_bounds__(256) void k4_idft_m(const float2* __restrict__ oft,
                                                 float2* __restrict__ T)
{
    __shared__ float2 Os[32][64];
    __shared__ float tc[128], tsn[128];
    const int t = threadIdx.x;
    const int b = blockIdx.x >> 4, q = blockIdx.x & 15;
    if (t < 128) { float a = t * (TWO_PI / 128.0f); tc[t] = cosf(a); tsn[t] = sinf(a); }
    for (int k = t; k < 2048; k += 256) {
        int p = k >> 6, o = k & 63;
        Os[p][o] = oft[((size_t)(b * 32 + p) * 16 + q) * 64 + o];
    }
    __syncthreads();
    const int o = t & 63;
    const int u0 = (t >> 6) << 5;
    float2 op[32];
    #pragma unroll
    for (int p = 0; p < 32; ++p) op[p] = Os[p][o];
    for (int du = 0; du < 32; ++du) {
        int u = u0 + du;
        float ax = 0.f, ay = 0.f;
        #pragma unroll
        for (int p = 0; p < 32; ++p) {
            int km = (p < 16) ? p : (96 + p);
            int idx = (km * u) & 127;
            float c = tc[idx], s = tsn[idx];
            ax += op[p].x * c - op[p].y * s;      // a * e^{+i th}
            ay += op[p].x * s + op[p].y * c;
        }
        T[((size_t)(b * 128 + u) * 16 + q) * 64 + o] = make_float2(ax, ay);
    }
}

// k5: y[b,u,v,o] = relu( (1/128)*(Re T[u,0,o] + 2*sum_{q=1..15} Re(T[u,q,o] e^{2pi i q v/128}))
//                        + sum_i x[b,u,v,i]*w_lin[i,o] + b_lin[o] )   -> bf16
__global__ __launch_bounds__(256) void k5_assemble(const float* __restrict__ x,
                                                   const float2* __restrict__ T,
                                                   const float* __restrict__ wl,
                                                   const float* __restrict__ bl,
                                                   unsigned short* __restrict__ y)
{
    __shared__ float xs[128][65];
    __shared__ __align__(16) float2 Ts[16][64];
    __shared__ __align__(16) float wls[64 * 64];
    __shared__ float bls[64];
    __shared__ float tc[128], tsn[128];
    const int t = threadIdx.x;
    const int bm = blockIdx.x;   // b*128 + u
    if (t < 128) { float a = t * (TWO_PI / 128.0f); tc[t] = cosf(a); tsn[t] = sinf(a); }
    const float4* xg4 = (const float4*)(x + (size_t)bm * 8192);
    for (int k = t; k < 2048; k += 256) {
        float4 v = xg4[k]; int r = k >> 4, c = (k & 15) << 2;
        xs[r][c] = v.x; xs[r][c + 1] = v.y; xs[r][c + 2] = v.z; xs[r][c + 3] = v.w;
    }
    const float2* Tg = T + (size_t)bm * 1024;
    for (int k = t; k < 1024; k += 256) ((float2*)Ts)[k] = Tg[k];
    for (int k = t; k < 1024; k += 256) ((float4*)wls)[k] = ((const float4*)wl)[k];
    if (t < 64) bls[t] = bl[t];
    __syncthreads();
    const int o0 = (t & 15) << 2;
    const int vb = t >> 4;               // v = vb + 16*vv
    float acc[8][4];
    #pragma unroll
    for (int vv = 0; vv < 8; ++vv)
        #pragma unroll
        for (int oo = 0; oo < 4; ++oo) acc[vv][oo] = bls[o0 + oo];
    for (int i = 0; i < 64; ++i) {
        float w[4];
        *(float4*)w = *(const float4*)&wls[i * 64 + o0];
        #pragma unroll
        for (int vv = 0; vv < 8; ++vv) {
            float xv = xs[vb + 16 * vv][i];
            #pragma unroll
            for (int oo = 0; oo < 4; ++oo) acc[vv][oo] += xv * w[oo];
        }
    }
    {   // q = 0 term (irfft keeps only the real part of the DC bin)
        float t0[4];
        #pragma unroll
        for (int oo = 0; oo < 4; ++oo) t0[oo] = Ts[0][o0 + oo].x * (1.0f / 128.0f);
        #pragma unroll
        for (int vv = 0; vv < 8; ++vv)
            #pragma unroll
            for (int oo = 0; oo < 4; ++oo) acc[vv][oo] += t0[oo];
    }
    for (int q = 1; q < 16; ++q) {
        float2 tq[4];
        #pragma unroll
        for (int oo = 0; oo < 4; ++oo) tq[oo] = Ts[q][o0 + oo];
        #pragma unroll
        for (int vv = 0; vv < 8; ++vv) {
            int idx = (q * (vb + 16 * vv)) & 127;
            float c = tc[idx] * (1.0f / 64.0f);   // 2/128
            float s = tsn[idx] * (1.0f / 64.0f);
            #pragma unroll
            for (int oo = 0; oo < 4; ++oo)
                acc[vv][oo] += tq[oo].x * c - tq[oo].y * s;
        }
    }
    unsigned short* yg = y + (size_t)bm * 8192;
    #pragma unroll
    for (int vv = 0; vv < 8; ++vv) {
        int v = vb + 16 * vv;
        ushort4 r;
        r.x = f2bf(fmaxf(acc[vv][0], 0.f)); r.y = f2bf(fmaxf(acc[vv][1], 0.f));
        r.z = f2bf(fmaxf(acc[vv][2], 0.f)); r.w = f2bf(fmaxf(acc[vv][3], 0.f));
        *(ushort4*)&yg[v * 64 + o0] = r;
    }
}

// k6: both heads via bf16 MFMA. 64 rows/block, 4 waves.
// GEMM1: [64x64]@[64x128] -> relu -> bf16 ; GEMM2: [64x128]@[128x64] -> +b2 -> out
__global__ __launch_bounds__(256) void k6_heads_mfma(
    const unsigned short* __restrict__ y,    // [524288][64] bf16
    const unsigned short* __restrict__ w1bt, // [2][128][64] bf16 (o-major, k inner)
    const unsigned short* __restrict__ w2bt, // [2][64][128] bf16
    const float* __restrict__ bb1, const float* __restrict__ bb2,
    const float* __restrict__ bf1, const float* __restrict__ bf2,
    float* __restrict__ out)
{
    __shared__ unsigned short ys[64][72];    //  9216 B
    __shared__ unsigned short hs[64][136];   // 17408 B
    __shared__ unsigned short w1s[128][72];  // 18432 B
    __shared__ unsigned short w2s[64][136];  // 17408 B
    __shared__ float b1s[128], b2s[64];
    const int t = threadIdx.x;
    const int lane = t & 63, wv = t >> 6;
    const int ar = lane & 15, kg = lane >> 4;
    const size_t rbase = (size_t)blockIdx.x * 64;

    // stage y tile: 64x64 bf16
    {
        const unsigned short* yg = y + rbase * 64;
        for (int k = t; k < 512; k += 256) {
            int row = k >> 3, col = (k & 7) * 8;
            *(uint4*)&ys[row][col] = *(const uint4*)(yg + row * 64 + col);
        }
    }

    for (int head = 0; head < 2; ++head) {
        if (head) __syncthreads();   // prev head's GEMM2 done before W overwrite
        const unsigned short* g1 = w1bt + head * 8192;
        for (int k = t; k < 1024; k += 256) {
            int row = k >> 3, col = (k & 7) * 8;
            *(uint4*)&w1s[row][col] = *(const uint4*)(g1 + row * 64 + col);
        }
        const unsigned short* g2 = w2bt + head * 8192;
        for (int k = t; k < 1024; k += 256) {
            int row = k >> 4, col = (k & 15) * 8;
            *(uint4*)&w2s[row][col] = *(const uint4*)(g2 + row * 128 + col);
        }
        const float* B1 = head ? bf1 : bb1;
        const float* B2 = head ? bf2 : bb2;
        if (t < 128) b1s[t] = B1[t];
        if (t < 64)  b2s[t] = B2[t];
        __syncthreads();

        // GEMM1: out 64x128; wave wv owns cols [wv*32, wv*32+32)
        f32x4 acc1[4][2];
        #pragma unroll
        for (int rt = 0; rt < 4; ++rt) {
            acc1[rt][0] = (f32x4){0.f, 0.f, 0.f, 0.f};
            acc1[rt][1] = (f32x4){0.f, 0.f, 0.f, 0.f};
        }
        #pragma unroll
        for (int ks = 0; ks < 2; ++ks) {
            int k0 = ks * 32 + kg * 8;
            bf16x8 b0 = *(const bf16x8*)&w1s[wv * 32 + ar][k0];
            bf16x8 b1 = *(const bf16x8*)&w1s[wv * 32 + 16 + ar][k0];
            #pragma unroll
            for (int rt = 0; rt < 4; ++rt) {
                bf16x8 a = *(const bf16x8*)&ys[rt * 16 + ar][k0];
                acc1[rt][0] = __builtin_amdgcn_mfma_f32_16x16x32_bf16(a, b0, acc1[rt][0], 0, 0, 0);
                acc1[rt][1] = __builtin_amdgcn_mfma_f32_16x16x32_bf16(a, b1, acc1[rt][1], 0, 0, 0);
            }
        }
        // epilogue 1: +bias, relu, bf16 -> hs
        #pragma unroll
        for (int rt = 0; rt < 4; ++rt)
            #pragma unroll
            for (int ct = 0; ct < 2; ++ct) {
                int col = wv * 32 + ct * 16 + ar;
                float bias = b1s[col];
                #pragma unroll
                for (int r = 0; r < 4; ++r) {
                    float v = fmaxf(acc1[rt][ct][r] + bias, 0.f);
                    hs[rt * 16 + kg * 4 + r][col] = f2bf(v);
                }
            }
        __syncthreads();

        // GEMM2: out 64x64; wave wv owns cols [wv*16, wv*16+16)
        f32x4 acc2[4];
        #pragma unroll
        for (int rt = 0; rt < 4; ++rt) acc2[rt] = (f32x4){0.f, 0.f, 0.f, 0.f};
        #pragma unroll
        for (int ks = 0; ks < 4; ++ks) {
            int k0 = ks * 32 + kg * 8;
            bf16x8 b = *(const bf16x8*)&w2s[wv * 16 + ar][k0];
            #pragma unroll
            for (int rt = 0; rt < 4; ++rt) {
                bf16x8 a = *(const bf16x8*)&hs[rt * 16 + ar][k0];
                acc2[rt] = __builtin_amdgcn_mfma_f32_16x16x32_bf16(a, b, acc2[rt], 0, 0, 0);
            }
        }
        float* og = out + (size_t)head * 33554432u + rbase * 64;
        int col = wv * 16 + ar;
        float bias2 = b2s[col];
        #pragma unroll
        for (int rt = 0; rt < 4; ++rt)
            #pragma unroll
            for (int r = 0; r < 4; ++r)
                og[(size_t)(rt * 16 + kg * 4 + r) * 64 + col] = acc2[rt][r] + bias2;
    }
}

extern "C" void kernel_launch(void* const* d_in, const int* in_sizes, int n_in,
                              void* d_out, int out_size, void* d_ws, size_t ws_size,
                              hipStream_t stream)
{
    (void)in_sizes; (void)n_in; (void)out_size; (void)ws_size;
    const float* x   = (const float*)d_in[0];
    const float* ws0 = (const float*)d_in[1];
    const float* ws1 = (const float*)d_in[2];
    const float* wl  = (const float*)d_in[3];
    const float* bl  = (const float*)d_in[4];
    const float* wb1 = (const float*)d_in[5];
    const float* bb1 = (const float*)d_in[6];
    const float* wb2 = (const float*)d_in[7];
    const float* bb2 = (const float*)d_in[8];
    const float* wf1 = (const float*)d_in[9];
    const float* bf1 = (const float*)d_in[10];
    const float* wf2 = (const float*)d_in[11];
    const float* bf2 = (const float*)d_in[12];
    float* out = (float*)d_out;

    float* ws = (float*)d_ws;
    float2* w0t = (float2*)ws;                     // 131072 float2
    float2* w1t = (float2*)(ws + 262144);          // 131072 float2
    float2* Tb  = (float2*)(ws + 524288);          // 4194304 float2
    float2* Ab  = (float2*)(ws + 8912896);         // 4194304 float2 (dead after k2)
    unsigned short* yb = (unsigned short*)(ws + 8912896);  // 33554432 bf16, spans to float 25690112
    float2* xft = (float2*)(ws + 17301504);        // 1048576 float2 (dead after k3a)
    float2* c1b = (float2*)(ws + 19398656);        // 1048576 float2 (dead after k3b)
    float2* oft = (float2*)(ws + 21495808);        // 1048576 float2 (dead after k4)
    unsigned short* w1bt = (unsigned short*)(ws + 25690112);  // 16384 bf16, PAST y
    unsigned short* w2bt = w1bt + 16384;                      // 16384 bf16

    k0_prep    <<<1024, 256, 0, stream>>>(ws0, ws1, w0t, w1t);
    k0b_prep   <<<128,  256, 0, stream>>>(wb1, wf1, wb2, wf2, w1bt, w2bt);
    k1_dft_n   <<<4096, 256, 0, stream>>>(x, Ab);
    k2_dft_m   <<<512,  256, 0, stream>>>(Ab, xft);
    k3a_spec1  <<<1024, 256, 0, stream>>>(xft, w0t, c1b);
    k3b_spec2  <<<1024, 256, 0, stream>>>(c1b, w1t, oft);
    k4_idft_m  <<<512,  256, 0, stream>>>(oft, Tb);
    k5_assemble<<<4096, 256, 0, stream>>>(x, Tb, wl, bl, yb);
    k6_heads_mfma<<<8192, 256, 0, stream>>>(yb, w1bt, w2bt, bb1, bb2, bf1, bf2, out);
}

// Round 4
// 454.551 us; speedup vs baseline: 2.3488x; 1.0228x over previous
//
#include <hip/hip_runtime.h>
#include <hip/hip_bf16.h>

#define TWO_PI 6.28318530717958647692f

typedef __attribute__((ext_vector_type(8))) short bf16x8;
typedef __attribute__((ext_vector_type(4))) float f32x4;

__device__ __forceinline__ unsigned short f2bf(float v) {
    __hip_bfloat16 h = __float2bfloat16(v);
    return *(unsigned short*)&h;
}

// Problem: B=32, M=N=128, I=O=64, NM=16.
// Spectral path keeps only km in {0..15, 112..127} (p=0..31) and kn=0..15 (q).
// Spectral branch contributes ~1e-6 absolute to y (tiny xavier weights), so its
// precision budget is huge; residual branch (x@w_lin) stays fp32.
//
// ws layout (float offsets):
//   w0t  @ 0        : 262144   (32 p x 64 i x 64 j complex)
//   w1t  @ 262144   : 262144   (2 h x 16 kv x 64 j x 64 o complex)
//   T    @ 524288   : 8388608  ([b][u][q][o] complex)
//   A    @ 8912896  : 8388608  ([b][m][kv][i] complex)  (dead after k2)
//   xft  @ 17301504 : 2097152  (dead after k3a)
//   c1   @ 19398656 : 2097152  (dead after k3b)
//   oft  @ 21495808 : 2097152  (dead after k4)
//   wbt  @ 23592960 : 32768 bf16 W1t + 32768 bf16 W2t
// y no longer exists in HBM (fused k56 keeps it in LDS).

__global__ __launch_bounds__(256) void k0_prep(const float* __restrict__ ws0,
                                               const float* __restrict__ ws1,
                                               float2* __restrict__ w0t,
                                               float2* __restrict__ w1t)
{
    int tgt = blockIdx.x * 256 + threadIdx.x;   // 0..262143
    if (tgt < 131072) {
        int p = tgt >> 12;
        int rem = tgt & 4095;
        int i = rem >> 6, j = rem & 63;
        const float* s = (p < 16) ? ws0 : ws1;   // f=0 plane
        int px = p & 15;
        int base = ((i * 64 + j) * 16 + px) * 2;
        w0t[tgt] = make_float2(s[base], s[base + 1]);
    } else {
        int u = tgt - 131072;
        int h = u >> 16;
        int kv = (u >> 12) & 15;
        int j = (u >> 6) & 63;
        int o = u & 63;
        const float* s = (h ? ws1 : ws0) + 131072;  // f=1 plane
        int base = ((j * 64 + o) * 16 + kv) * 2;
        w1t[u] = make_float2(s[base], s[base + 1]);
    }
}

// bf16 transposed head weights: W1t[head][o:128][k:64], W2t[head][o:64][k:128]
__global__ __launch_bounds__(256) void k0b_prep(const float* __restrict__ wb1,
                                                const float* __restrict__ wf1,
                                                const float* __restrict__ wb2,
                                                const float* __restrict__ wf2,
                                                unsigned short* __restrict__ w1bt,
                                                unsigned short* __restrict__ w2bt)
{
    int tgt = blockIdx.x * 256 + threadIdx.x;   // 0..32767
    if (tgt < 16384) {
        int head = tgt >> 13;
        int o = (tgt >> 6) & 127;
        int i = tgt & 63;
        const float* src = head ? wf1 : wb1;    // [64][128]
        w1bt[tgt] = f2bf(src[i * 128 + o]);
    } else {
        int u = tgt - 16384;
        int head = u >> 13;
        int o = (u >> 7) & 63;
        int c = u & 127;
        const float* src = head ? wf2 : wb2;    // [128][64]
        w2bt[u] = f2bf(src[c * 64 + o]);
    }
}

// k1: A[b,m,kv,i] = sum_n x[b,m,n,i] * exp(-2pi i kv n/128), kv=0..15
__global__ __launch_bounds__(256) void k1_dft_n(const float* __restrict__ x,
                                                float2* __restrict__ A)
{
    __shared__ float Xs[128][64];
    __shared__ __align__(8) float2 tcs[128];
    const int t = threadIdx.x;
    const int bm = blockIdx.x;
    if (t < 128) { float a = t * (TWO_PI / 128.0f); tcs[t] = make_float2(cosf(a), sinf(a)); }
    const float4* xg4 = (const float4*)(x + (size_t)bm * 8192);
    float4* Xs4 = (float4*)&Xs[0][0];
    for (int k = t; k < 2048; k += 256) Xs4[k] = xg4[k];
    __syncthreads();
    const int i = t & 63;
    const int kv0 = (t >> 6) << 2;
    float re[4] = {0.f, 0.f, 0.f, 0.f}, im[4] = {0.f, 0.f, 0.f, 0.f};
    for (int n = 0; n < 128; ++n) {
        float v = Xs[n][i];
        #pragma unroll
        for (int j = 0; j < 4; ++j) {
            int idx = ((kv0 + j) * n) & 127;
            float2 w = tcs[idx];
            re[j] += v * w.x;
            im[j] -= v * w.y;
        }
    }
    float2* Ap = A + (size_t)bm * 1024;
    #pragma unroll
    for (int j = 0; j < 4; ++j) Ap[(kv0 + j) * 64 + i] = make_float2(re[j], im[j]);
}

// k2: xft[b,p,kv,i] = (1/128) sum_m A[b,m,kv,i] * exp(-2pi i km(p) m/128)
__global__ __launch_bounds__(256) void k2_dft_m(const float2* __restrict__ A,
                                                float2* __restrict__ xft)
{
    __shared__ float2 As[128][64];
    __shared__ __align__(8) float2 tcs[128];
    const int t = threadIdx.x;
    const int b = blockIdx.x >> 4, kv = blockIdx.x & 15;
    if (t < 128) { float a = t * (TWO_PI / 128.0f); tcs[t] = make_float2(cosf(a), sinf(a)); }
    for (int k = t; k < 8192; k += 256) {
        int m = k >> 6, i = k & 63;
        As[m][i] = A[((size_t)(b * 128 + m) * 16 + kv) * 64 + i];
    }
    __syncthreads();
    const int i = t & 63;
    const int p0 = (t >> 6) << 3;
    float2 acc[8];
    #pragma unroll
    for (int j = 0; j < 8; ++j) acc[j] = make_float2(0.f, 0.f);
    for (int m = 0; m < 128; ++m) {
        float2 a = As[m][i];
        #pragma unroll
        for (int j = 0; j < 8; ++j) {
            int p = p0 + j;
            int km = (p < 16) ? p : (96 + p);     // p>=16 -> km = 112 + (p-16)
            int idx = (km * m) & 127;
            float2 cs = tcs[idx];
            acc[j].x += a.x * cs.x + a.y * cs.y;  // a * e^{-i th}
            acc[j].y += a.y * cs.x - a.x * cs.y;
        }
    }
    const float sc = 1.0f / 128.0f;
    #pragma unroll
    for (int j = 0; j < 8; ++j)
        xft[((size_t)(b * 32 + p0 + j) * 16 + kv) * 64 + i] =
            make_float2(acc[j].x * sc, acc[j].y * sc);
}

// k3a: c1[b,p,kv,j] = sum_i xft[b,p,kv,i] * w0c[i,j,p]
__global__ __launch_bounds__(256) void k3a_spec1(const float2* __restrict__ xft,
                                                 const float2* __restrict__ w0t,
                                                 float2* __restrict__ c1)
{
    __shared__ __align__(16) float2 xs[16][64];
    __shared__ __align__(16) float2 w0s[64][64];
    const int t = threadIdx.x;
    const int b = blockIdx.x >> 5, p = blockIdx.x & 31;
    const float2* xg = xft + (size_t)(b * 32 + p) * 1024;
    for (int k = t; k < 1024; k += 256) ((float2*)xs)[k] = xg[k];
    const float4* wg = (const float4*)(w0t + (size_t)p * 4096);
    for (int k = t; k < 2048; k += 256) ((float4*)w0s)[k] = wg[k];
    __syncthreads();
    const int j = t & 63;
    const int kv0 = (t >> 6) << 2;
    float2 acc[4];
    #pragma unroll
    for (int q = 0; q < 4; ++q) acc[q] = make_float2(0.f, 0.f);
    for (int i = 0; i < 64; ++i) {
        float2 w = w0s[i][j];
        #pragma unroll
        for (int q = 0; q < 4; ++q) {
            float2 a = xs[kv0 + q][i];
            acc[q].x += a.x * w.x - a.y * w.y;
            acc[q].y += a.x * w.y + a.y * w.x;
        }
    }
    #pragma unroll
    for (int q = 0; q < 4; ++q)
        c1[((size_t)(b * 32 + p) * 16 + kv0 + q) * 64 + j] = acc[q];
}

// k3b: oft[b,p,kv,o] = sum_j c1[b,p,kv,j] * w1c[j,o,kv]  (weights per half h=p/16)
__global__ __launch_bounds__(256) void k3b_spec2(const float2* __restrict__ c1,
                                                 const float2* __restrict__ w1t,
                                                 float2* __restrict__ oft)
{
    __shared__ __align__(16) float2 cs[16][64];
    __shared__ __align__(16) float2 w1s[64][64];
    const int t = threadIdx.x;
    int id = blockIdx.x;
    const int h = id & 1; id >>= 1;
    const int kv = id & 15; const int b = id >> 4;
    for (int k = t; k < 1024; k += 256) {
        int pp = k >> 6, j = k & 63;
        cs[pp][j] = c1[((size_t)(b * 32 + h * 16 + pp) * 16 + kv) * 64 + j];
    }
    const float4* wg = (const float4*)(w1t + (size_t)(h * 16 + kv) * 4096);
    for (int k = t; k < 2048; k += 256) ((float4*)w1s)[k] = wg[k];
    __syncthreads();
    const int o = t & 63;
    const int pp0 = (t >> 6) << 2;
    float2 acc[4];
    #pragma unroll
    for (int q = 0; q < 4; ++q) acc[q] = make_float2(0.f, 0.f);
    for (int j = 0; j < 64; ++j) {
        float2 w = w1s[j][o];
        #pragma unroll
        for (int q = 0; q < 4; ++q) {
            float2 a = cs[pp0 + q][j];
            acc[q].x += a.x * w.x - a.y * w.y;
            acc[q].y += a.x * w.y + a.y * w.x;
        }
    }
    #pragma unroll
    for (int q = 0; q < 4; ++q)
        oft[((size_t)(b * 32 + h * 16 + pp0 + q) * 16 + kv) * 64 + o] = acc[q];
}

// k4: T[b,u,q,o] = sum_p oft[b,p,q,o] * exp(+2pi i km(p) u/128)
__global__ __launch_bounds__(256) void k4_idft_m(const float2* __restrict__ oft,
                                                 float2* __restrict__ T)
{
    __shared__ float2 Os[32][64];
    __shared__ __align__(8) float2 tcs[128];
    const int t = threadIdx.x;
    const int b = blockIdx.x >> 4, q = blockIdx.x & 15;
    if (t < 128) { float a = t * (TWO_PI / 128.0f); tcs[t] = make_float2(cosf(a), sinf(a)); }
    for (int k = t; k < 2048; k += 256) {
        int p = k >> 6, o = k & 63;
        Os[p][o] = oft[((size_t)(b * 32 + p) * 16 + q) * 64 + o];
    }
    __syncthreads();
    const int o = t & 63;
    const int u0 = (t >> 6) << 5;
    float2 op[32];
    #pragma unroll
    for (int p = 0; p < 32; ++p) op[p] = Os[p][o];
    for (int du = 0; du < 32; ++du) {
        int u = u0 + du;
        float ax = 0.f, ay = 0.f;
        #pragma unroll
        for (int p = 0; p < 32; ++p) {
            int km = (p < 16) ? p : (96 + p);
            int idx = (km * u) & 127;
            float2 cs = tcs[idx];
            ax += op[p].x * cs.x - op[p].y * cs.y;  // a * e^{+i th}
            ay += op[p].x * cs.y + op[p].y * cs.x;
        }
        T[((size_t)(b * 128 + u) * 16 + q) * 64 + o] = make_float2(ax, ay);
    }
}

// k56: fused assemble (k5) + both head MLPs (k6). One block per bm=(b,u), 128 rows.
// Phase A (fp32 VALU): y = relu(irfft-assembly + x@w_lin + b_lin) -> bf16 ys in LDS.
// Phase B (bf16 MFMA): per head: h = relu(ys@W1+b1); out = h@W2+b2.
// LDS tiles ys/w1s/hs/w2s are unpadded with chunk-XOR swizzle (chunk ^= row&7)
// so b128 fragment reads are ~2-way (free) instead of bank-quad serialized.
__global__ __launch_bounds__(256) void k56_fused(
    const float* __restrict__ x, const float2* __restrict__ T,
    const float* __restrict__ wl, const float* __restrict__ bl,
    const unsigned short* __restrict__ w1bt, const unsigned short* __restrict__ w2bt,
    const float* __restrict__ bb1, const float* __restrict__ bb2,
    const float* __restrict__ bf1, const float* __restrict__ bf2,
    float* __restrict__ out)
{
    __shared__ __align__(16) unsigned char U[57856];   // phase A: xs|Ts|wls ; phase B: w1s|w2s|hs
    __shared__ __align__(16) unsigned short ys[128 * 64];
    __shared__ __align__(8) float2 tcs[128];
    __shared__ float bls[64];
    __shared__ float b1s[128], b2s[64];

    float* xs  = (float*)U;                    // [128][65] fp32
    float2* Ts = (float2*)(U + 33280);         // [16][64]
    float* wls = (float*)(U + 41472);          // [64][64]
    unsigned short* w1s = (unsigned short*)U;             // [128][64] bf16 swizzled
    unsigned short* w2s = (unsigned short*)(U + 16384);   // [64][128] bf16 swizzled
    unsigned short* hs  = (unsigned short*)(U + 32768);   // [64][128] bf16 swizzled

    const int t = threadIdx.x;
    const int bm = blockIdx.x;                 // b*128 + u
    const int lane = t & 63, wv = t >> 6;
    const int ar = lane & 15, kg = lane >> 4;

    // ---- stage phase A inputs ----
    if (t < 128) { float a = t * (TWO_PI / 128.0f); tcs[t] = make_float2(cosf(a), sinf(a)); }
    {
        const float4* xg4 = (const float4*)(x + (size_t)bm * 8192);
        for (int k = t; k < 2048; k += 256) {
            float4 v = xg4[k]; int r = k >> 4, c = (k & 15) << 2;
            float* row = xs + r * 65 + c;
            row[0] = v.x; row[1] = v.y; row[2] = v.z; row[3] = v.w;
        }
        const float2* Tg = T + (size_t)bm * 1024;
        for (int k = t; k < 1024; k += 256) Ts[k] = Tg[k];
        for (int k = t; k < 1024; k += 256) ((float4*)wls)[k] = ((const float4*)wl)[k];
        if (t < 64) bls[t] = bl[t];
    }
    __syncthreads();

    // ---- phase A compute: y rows, 8 per thread ----
    {
        const int o0 = (t & 15) << 2;
        const int vb = t >> 4;                 // v = vb + 16*vv
        float acc[8][4];
        #pragma unroll
        for (int vv = 0; vv < 8; ++vv)
            #pragma unroll
            for (int oo = 0; oo < 4; ++oo) acc[vv][oo] = bls[o0 + oo];
        for (int i = 0; i < 64; ++i) {
            float w[4];
            *(float4*)w = *(const float4*)&wls[i * 64 + o0];
            #pragma unroll
            for (int vv = 0; vv < 8; ++vv) {
                float xv = xs[(vb + 16 * vv) * 65 + i];
                #pragma unroll
                for (int oo = 0; oo < 4; ++oo) acc[vv][oo] += xv * w[oo];
            }
        }
        {   // q = 0 (irfft keeps only Re of DC bin)
            float4 t01 = *(const float4*)&Ts[o0];
            float4 t23 = *(const float4*)&Ts[o0 + 2];
            float t0[4] = {t01.x * (1.0f/128.0f), t01.z * (1.0f/128.0f),
                           t23.x * (1.0f/128.0f), t23.z * (1.0f/128.0f)};
            #pragma unroll
            for (int vv = 0; vv < 8; ++vv)
                #pragma unroll
                for (int oo = 0; oo < 4; ++oo) acc[vv][oo] += t0[oo];
        }
        for (int q = 1; q < 16; ++q) {
            float4 t01 = *(const float4*)&Ts[q * 64 + o0];
            float4 t23 = *(const float4*)&Ts[q * 64 + o0 + 2];
            float tre[4] = {t01.x, t01.z, t23.x, t23.z};
            float tim[4] = {t01.y, t01.w, t23.y, t23.w};
            #pragma unroll
            for (int vv = 0; vv < 8; ++vv) {
                int idx = (q * (vb + 16 * vv)) & 127;
                float2 cs = tcs[idx];
                float c = cs.x * (1.0f / 64.0f);   // 2/128
                float s = cs.y * (1.0f / 64.0f);
                #pragma unroll
                for (int oo = 0; oo < 4; ++oo)
                    acc[vv][oo] += tre[oo] * c - tim[oo] * s;
            }
        }
        // relu -> bf16 -> ys (swizzled)
        const int swc = (((o0 >> 3) ^ (vb & 7)) << 3) + (o0 & 7);
        #pragma unroll
        for (int vv = 0; vv < 8; ++vv) {
            int v = vb + 16 * vv;
            ushort4 r4;
            r4.x = f2bf(fmaxf(acc[vv][0], 0.f)); r4.y = f2bf(fmaxf(acc[vv][1], 0.f));
            r4.z = f2bf(fmaxf(acc[vv][2], 0.f)); r4.w = f2bf(fmaxf(acc[vv][3], 0.f));
            *(ushort4*)&ys[v * 64 + swc] = r4;
        }
    }
    __syncthreads();   // phase A reads of U done; ys visible

    // ---- phase B: heads ----
    for (int head = 0; head < 2; ++head) {
        const unsigned short* g1 = w1bt + head * 8192;
        for (int k = t; k < 1024; k += 256) {
            int row = k >> 3, ch = k & 7;
            *(uint4*)&w1s[row * 64 + ((ch ^ (row & 7)) << 3)] = *(const uint4*)(g1 + k * 8);
        }
        const unsigned short* g2 = w2bt + head * 8192;
        for (int k = t; k < 1024; k += 256) {
            int row = k >> 4, ch = k & 15;
            *(uint4*)&w2s[row * 128 + ((ch ^ (row & 7)) << 3)] = *(const uint4*)(g2 + k * 8);
        }
        const float* B1 = head ? bf1 : bb1;
        const float* B2 = head ? bf2 : bb2;
        if (t < 128) b1s[t] = B1[t];
        if (t < 64)  b2s[t] = B2[t];
        __syncthreads();

        for (int half = 0; half < 2; ++half) {
            // GEMM1: rows half*64 + wv*16 + [16], cols 128, K=64
            const int arow = half * 64 + wv * 16 + ar;
            f32x4 acc1[8];
            #pragma unroll
            for (int ct = 0; ct < 8; ++ct) acc1[ct] = (f32x4){0.f, 0.f, 0.f, 0.f};
            #pragma unroll
            for (int ks = 0; ks < 2; ++ks) {
                int ch = ks * 4 + kg;
                bf16x8 a = *(const bf16x8*)&ys[arow * 64 + ((ch ^ (arow & 7)) << 3)];
                #pragma unroll
                for (int ct = 0; ct < 8; ++ct) {
                    int brow = ct * 16 + ar;
                    bf16x8 b = *(const bf16x8*)&w1s[brow * 64 + ((ch ^ (brow & 7)) << 3)];
                    acc1[ct] = __builtin_amdgcn_mfma_f32_16x16x32_bf16(a, b, acc1[ct], 0, 0, 0);
                }
            }
            // epilogue: +b1, relu, bf16 -> hs (swizzled)
            #pragma unroll
            for (int ct = 0; ct < 8; ++ct) {
                int col = ct * 16 + ar;
                float bias = b1s[col];
                #pragma unroll
                for (int r = 0; r < 4; ++r) {
                    int row = wv * 16 + kg * 4 + r;
                    int sc = ((((col >> 3) ^ (row & 7))) << 3) + (col & 7);
                    hs[row * 128 + sc] = f2bf(fmaxf(acc1[ct][r] + bias, 0.f));
                }
            }
            __syncthreads();
            // GEMM2: rows (same 64), cols 64, K=128
            f32x4 acc2[4];
            #pragma unroll
            for (int ct = 0; ct < 4; ++ct) acc2[ct] = (f32x4){0.f, 0.f, 0.f, 0.f};
            const int arw = wv * 16 + ar;
            #pragma unroll
            for (int ks = 0; ks < 4; ++ks) {
                int ch = ks * 4 + kg;
                bf16x8 a = *(const bf16x8*)&hs[arw * 128 + ((ch ^ (arw & 7)) << 3)];
                #pragma unroll
                for (int ct = 0; ct < 4; ++ct) {
                    int brw = ct * 16 + ar;
                    bf16x8 b = *(const bf16x8*)&w2s[brw * 128 + ((ch ^ (brw & 7)) << 3)];
                    acc2[ct] = __builtin_amdgcn_mfma_f32_16x16x32_bf16(a, b, acc2[ct], 0, 0, 0);
                }
            }
            float* og = out + (size_t)head * 33554432u + (size_t)bm * 8192 + half * 4096;
            #pragma unroll
            for (int ct = 0; ct < 4; ++ct) {
                float bias2 = b2s[ct * 16 + ar];
                #pragma unroll
                for (int r = 0; r < 4; ++r)
                    og[(wv * 16 + kg * 4 + r) * 64 + ct * 16 + ar] = acc2[ct][r] + bias2;
            }
            __syncthreads();   // hs reads done before half1 / next head staging
        }
    }
}

extern "C" void kernel_launch(void* const* d_in, const int* in_sizes, int n_in,
                              void* d_out, int out_size, void* d_ws, size_t ws_size,
                              hipStream_t stream)
{
    (void)in_sizes; (void)n_in; (void)out_size; (void)ws_size;
    const float* x   = (const float*)d_in[0];
    const float* ws0 = (const float*)d_in[1];
    const float* ws1 = (const float*)d_in[2];
    const float* wl  = (const float*)d_in[3];
    const float* bl  = (const float*)d_in[4];
    const float* wb1 = (const float*)d_in[5];
    const float* bb1 = (const float*)d_in[6];
    const float* wb2 = (const float*)d_in[7];
    const float* bb2 = (const float*)d_in[8];
    const float* wf1 = (const float*)d_in[9];
    const float* bf1 = (const float*)d_in[10];
    const float* wf2 = (const float*)d_in[11];
    const float* bf2 = (const float*)d_in[12];
    float* out = (float*)d_out;

    float* ws = (float*)d_ws;
    float2* w0t = (float2*)ws;                     // 131072 float2
    float2* w1t = (float2*)(ws + 262144);          // 131072 float2
    float2* Tb  = (float2*)(ws + 524288);          // 4194304 float2
    float2* Ab  = (float2*)(ws + 8912896);         // 4194304 float2 (dead after k2)
    float2* xft = (float2*)(ws + 17301504);        // 1048576 float2 (dead after k3a)
    float2* c1b = (float2*)(ws + 19398656);        // 1048576 float2 (dead after k3b)
    float2* oft = (float2*)(ws + 21495808);        // 1048576 float2 (dead after k4)
    unsigned short* w1bt = (unsigned short*)(ws + 23592960);  // 16384 bf16
    unsigned short* w2bt = w1bt + 16384;                      // 16384 bf16

    k0_prep    <<<1024, 256, 0, stream>>>(ws0, ws1, w0t, w1t);
    k0b_prep   <<<128,  256, 0, stream>>>(wb1, wf1, wb2, wf2, w1bt, w2bt);
    k1_dft_n   <<<4096, 256, 0, stream>>>(x, Ab);
    k2_dft_m   <<<512,  256, 0, stream>>>(Ab, xft);
    k3a_spec1  <<<1024, 256, 0, stream>>>(xft, w0t, c1b);
    k3b_spec2  <<<1024, 256, 0, stream>>>(c1b, w1t, oft);
    k4_idft_m  <<<512,  256, 0, stream>>>(oft, Tb);
    k56_fused  <<<4096, 256, 0, stream>>>(x, Tb, wl, bl, w1bt, w2bt,
                                          bb1, bb2, bf1, bf2, out);
}